// Round 8
// baseline (204.046 us; speedup 1.0000x reference)
//
#include <hip/hip_runtime.h>

// MinVarianceWeightsLayer: for each of B SPD 64x64 fp32 matrices S,
// solve S z = 1, output w = z / sum(z) as [B, 64, 1] fp32.
//
// ROUND-16: TWO matrices per wave. r15's intra-matrix cross-panel pipeline
// was neutral (~2us): one matrix's dependency graph has no more cheap
// textual ILP, and at ~2.25 resident waves/SIMD there's no TLP to hide the
// rest. The untouched resource is the register file: all session rounds
// used <=68 VGPRs. Interleave two INDEPENDENT eliminations statement-by-
// statement in one wave: phase-1 col_c(M0) covered by col_c(M1) (each
// ~60cyc rlane->rcp->nf chain); phase-3 runs A(M0-DS),A(M1-DS),B(M0-RL),
// B(M1-RL),C(M0),C(M1) so DS round trips are covered by ~256 cyc of the
// twin's VALU work. Dual-pipe x=1/2 split retained (r14-calibrated:
// DS per-CU 12cyc/b128, VALU per-SIMD ~3.7cyc/instr).
// Registers: r[2][32]=128 + lo/hi[2][4]x2=64 + state ~30 => ~220.
// waves_per_eu(2,2): 256-reg budget, 2 waves/SIMD; streams/SIMD 2.25->4.
// Algorithm per matrix unchanged from r14 (Gauss-Jordan, one-wave, no
// barriers, symmetric-trailing-block publish; validated absmax 2.441e-4).

#define NN 64

typedef float v2f __attribute__((ext_vector_type(2)));
typedef float v4f __attribute__((ext_vector_type(4)));

template <int I> struct ic { static constexpr int value = I; };

template <int Start, int End, typename F>
__device__ __forceinline__ void static_for(F&& f) {
    if constexpr (Start < End) {
        f(ic<Start>{});
        static_for<Start + 1, End>(static_cast<F&&>(f));
    }
}

__device__ __forceinline__ float rlane(float v, int lane) {
    return __int_as_float(__builtin_amdgcn_readlane(__float_as_int(v), lane));
}

__device__ __forceinline__ float frcp(float x) {
#if __has_builtin(__builtin_amdgcn_rcpf)
    return __builtin_amdgcn_rcpf(x);   // ~1 ulp; plenty vs 2e-3 abs threshold
#else
    return 1.0f / x;
#endif
}

__device__ __forceinline__ v2f fma2(v2f a, v2f b, v2f c) {
#if __has_builtin(__builtin_elementwise_fma)
    return __builtin_elementwise_fma(a, b, c);   // -> v_pk_fma_f32
#else
    v2f r; r.x = fmaf(a.x, b.x, c.x); r.y = fmaf(a.y, b.y, c.y); return r;
#endif
}

__global__
__attribute__((amdgpu_flat_work_group_size(256, 256), amdgpu_waves_per_eu(2, 2)))
void minvar_kernel(const float* __restrict__ sigma,
                   float* __restrict__ out,
                   int batch) {
    // [wave][mat][panel parity][ m*8 + c*2 + par ] : u_c[2m+par]
    __shared__ float pb[4][2][2][256];   // 16 KB/block

    const int lane = threadIdx.x & 63;
    const int wid  = threadIdx.x >> 6;       // 4 waves/block, 2 matrices each
    const int bid0 = blockIdx.x * 8 + wid * 2;
    if (bid0 >= batch) return;               // no barriers anywhere -> safe
    const int bid1 = bid0 + 1;
    const int cb1  = (bid1 < batch) ? bid1 : bid0;   // clamp (harmless dup work)

    const float* __restrict__ p0 = sigma + (size_t)bid0 * (NN * NN) + (size_t)lane * NN;
    const float* __restrict__ p1 = sigma + (size_t)cb1  * (NN * NN) + (size_t)lane * NN;

    // lane i's row of each matrix as 32 float2 pairs (compile-time idx -> VGPRs)
    v2f r[2][NN / 2];
    static_for<0, NN / 4>([&](auto j4c) {
        constexpr int j4 = decltype(j4c)::value;
        v4f v0 = reinterpret_cast<const v4f*>(p0)[j4];
        v4f v1 = reinterpret_cast<const v4f*>(p1)[j4];
        r[0][2 * j4 + 0] = v2f{v0.x, v0.y};
        r[0][2 * j4 + 1] = v2f{v0.z, v0.w};
        r[1][2 * j4 + 0] = v2f{v1.x, v1.y};
        r[1][2 * j4 + 1] = v2f{v1.z, v1.w};
    });

    float bb[2] = {1.0f, 1.0f};          // RHS: ones
    float dd[2] = {1.0f, 1.0f};          // per-lane pivot (set exactly once)
    const int wbase = (lane >> 1) * 8 + (lane & 1);   // scatter-write index

    static_for<0, 16>([&](auto pc) {
        constexpr int P  = decltype(pc)::value;
        constexpr int m0 = 2 * P;            // pair-slots m0, m0+1 are the panel
        float* __restrict__ wbm[2] = { &pb[wid][0][P & 1][0],
                                       &pb[wid][1][P & 1][0] };

        float el[2][4], nf[2][4];            // compile-time indexed -> registers

        // ---- phase 1: in-panel Jordan elimination, columns interleaved
        //      across the two matrices: c0(M0),c0(M1),c1(M0),c1(M1),...
        static_for<0, 4>([&](auto cc) {
            constexpr int C = decltype(cc)::value;
            constexpr int k = 4 * P + C;
            static_for<0, 2>([&](auto Mc) {
                constexpr int M  = decltype(Mc)::value;
                constexpr int mm = m0 + (C >> 1);
                const float e = (C & 1) ? r[M][mm].y : r[M][mm].x;
                if constexpr (P < 15) wbm[M][wbase + 2 * C] = e;   // publish early
                const float piv = rlane(e, k);
                const float f   = (lane != k) ? (-e * frcp(piv)) : 0.0f;
                dd[M] = (lane == k) ? e : dd[M];
                bb[M] = fmaf(f, rlane(bb[M], k), bb[M]);
                // update remaining panel columns C+1..3
                static_for<C + 1, 4>([&](auto jc) {
                    constexpr int J  = decltype(jc)::value;
                    constexpr int mj = m0 + (J >> 1);
                    float v = (J & 1) ? r[M][mj].y : r[M][mj].x;
                    v = fmaf(f, rlane(v, k), v);
                    if constexpr (J & 1) r[M][mj].y = v; else r[M][mj].x = v;
                });
                el[M][C] = e; nf[M][C] = f;
            });
        });

        if constexpr (P < 15) {
            // ---- phase 3: rank-4 update, dual-pipe x=1/2, cross-matrix
            //      covering: A0,A1 (DS issue) -> B0,B1 (readlane) -> C0,C1.
            static_for<0, 4>([&](auto gc) {
                constexpr int G = decltype(gc)::value;
                constexpr int s = m0 + 2 + 8 * G;
                if constexpr (s < NN / 2) {
                    constexpr int e_ = (s + 8 < NN / 2) ? (s + 8) : (NN / 2);
                    v4f lo[2][4], hi[2][4];
                    // pass A: issue DS reads (slots q=0..3), both matrices
                    static_for<0, 2>([&](auto Mc) {
                        constexpr int M = decltype(Mc)::value;
                        static_for<s, e_>([&](auto mc2) {
                            constexpr int m = decltype(mc2)::value;
                            constexpr int q = m - s;
                            if constexpr (q < 4) {
                                lo[M][q] = *reinterpret_cast<const v4f*>(wbm[M] + 8 * m);
                                hi[M][q] = *reinterpret_cast<const v4f*>(wbm[M] + 8 * m + 4);
                            }
                        });
                    });
                    // pass B: readlane slots (q=4..7), both matrices —
                    // ~256 VALU cycles of DS-independent work
                    static_for<0, 2>([&](auto Mc) {
                        constexpr int M = decltype(Mc)::value;
                        static_for<s, e_>([&](auto mc2) {
                            constexpr int m = decltype(mc2)::value;
                            constexpr int q = m - s;
                            if constexpr (q >= 4) {
                                constexpr int j0 = 2 * m, j1 = 2 * m + 1;
                                float ax = r[M][m].x, ay = r[M][m].y;
                                static_for<0, 4>([&](auto cc2) {
                                    constexpr int C = decltype(cc2)::value;
                                    ax = fmaf(nf[M][C], rlane(el[M][C], j0), ax);
                                    ay = fmaf(nf[M][C], rlane(el[M][C], j1), ay);
                                });
                                r[M][m] = v2f{ax, ay};
                            }
                        });
                    });
                    // pass C: consume prefetched LDS data (q=0..3)
                    static_for<0, 2>([&](auto Mc) {
                        constexpr int M = decltype(Mc)::value;
                        const v2f n0 = v2f{nf[M][0], nf[M][0]};
                        const v2f n1 = v2f{nf[M][1], nf[M][1]};
                        const v2f n2 = v2f{nf[M][2], nf[M][2]};
                        const v2f n3 = v2f{nf[M][3], nf[M][3]};
                        static_for<s, e_>([&](auto mc2) {
                            constexpr int m = decltype(mc2)::value;
                            constexpr int q = m - s;
                            if constexpr (q < 4) {
                                v2f acc = r[M][m];
                                acc = fma2(n0, v2f{lo[M][q].x, lo[M][q].y}, acc);
                                acc = fma2(n1, v2f{lo[M][q].z, lo[M][q].w}, acc);
                                acc = fma2(n2, v2f{hi[M][q].x, hi[M][q].y}, acc);
                                acc = fma2(n3, v2f{hi[M][q].z, hi[M][q].w}, acc);
                                r[M][m] = acc;
                            }
                        });
                    });
                }
            });
        }
    });

    // ---- diagonal system + normalize, per matrix ----
    static_for<0, 2>([&](auto Mc) {
        constexpr int M = decltype(Mc)::value;
        const float z = bb[M] * frcp(dd[M]);
        float tot = z;
        #pragma unroll
        for (int off = 32; off >= 1; off >>= 1)
            tot += __shfl_xor(tot, off, 64);
        const int ob = bid0 + M;
        if (M == 0 || ob < batch)
            out[(size_t)ob * NN + lane] = z * frcp(tot);
    });
}

extern "C" void kernel_launch(void* const* d_in, const int* in_sizes, int n_in,
                              void* d_out, int out_size, void* d_ws, size_t ws_size,
                              hipStream_t stream) {
    const float* sigma = (const float*)d_in[0];
    float* out = (float*)d_out;
    const int batch  = in_sizes[0] / (NN * NN);   // 8192
    const int blocks = (batch + 7) / 8;           // 8 matrices per 256-thr block
    minvar_kernel<<<blocks, 256, 0, stream>>>(sigma, out, batch);
}